// Round 13
// baseline (70.879 us; speedup 1.0000x reference)
//
#include <hip/hip_runtime.h>
#include <hip/hip_bf16.h>

#define BTOT 128     // B*T
#define NN   512
#define FIN  128
#define FOUT 64

typedef __attribute__((ext_vector_type(8))) short bf16x8;
typedef __attribute__((ext_vector_type(4))) float f32x4;

static __device__ inline ushort f2bf(float f) {
    __hip_bfloat16 h = __float2bfloat16(f);
    return *(ushort*)&h;
}
static __device__ inline float bf2f(ushort u) {
    uint v = (uint)u << 16;
    return __uint_as_float(v);
}

// ---------- P: prep W split (blocks 256..287) + cd pack (blocks 0..255) ----------
// cd ushort: bits15..1 = w*log2e RNE to 7-bit mantissa; bit0 = "p nonzero".
// p = m ? exp2(c * leaky(s)) : 0 reproduces every ref corner case (see R7).
__global__ void k_prep(const float* __restrict__ W, const int* __restrict__ adj,
                       const float* __restrict__ we, ushort* __restrict__ Whi,
                       ushort* __restrict__ Wlo, ushort* __restrict__ cds) {
    int b = blockIdx.x;
    if (b >= 256) {       // W split: 8192 elems over 32 blocks
        int i = (b - 256) * 256 + threadIdx.x;
        float w = W[i];
        ushort hi = f2bf(w);
        Whi[i] = hi;
        Wlo[i] = f2bf(w - bf2f(hi));
        return;
    }
    int i = (b * 256 + threadIdx.x) * 4;     // 262144 edges
    int4   a4 = *(const int4*)&adj[i];
    float4 w4 = *(const float4*)&we[i];
    ushort o[4];
#pragma unroll
    for (int e = 0; e < 4; ++e) {
        bool  cn = ((const int*)&a4)[e] > 0;
        float w  = ((const float*)&w4)[e];
        if (cn) {
            uint ub = __float_as_uint(w * 1.44269504f);
            uint tt = ub + 0xFFFFu + ((ub >> 17) & 1u);       // RNE @ 7-bit mantissa
            o[e] = (ushort)(((tt >> 17) << 1) | 1u);
        } else {
            o[e] = (w > 0.f) ? (ushort)0 : (ushort)1;         // p=0 | p=1
        }
    }
    *(uint2*)&cds[i] = *(uint2*)&o[0];
}

// ---------- A: h = x @ W^T via bf16x3 MFMA; emit ht bf16 [bt][o][n], src, dst ----
// 1D grid 1024, bid = ntile*128 + bt  =>  XCD = bt%8 (same XCD k_attn reads from).
__global__ void k_feat(const float* __restrict__ x, const ushort* __restrict__ Whi,
                       const ushort* __restrict__ Wlo, const float* __restrict__ a,
                       ushort* __restrict__ ht, float* __restrict__ srcv,
                       float* __restrict__ dstv) {
    const int t    = threadIdx.x;
    const int bid  = blockIdx.x;
    const int bt   = bid & 127;
    const int nt   = bid >> 7;
    const int wv   = t >> 6, lane = t & 63;
    const int r    = lane & 15;          // A-row / B-col within 16; C/D col
    const int kc   = lane >> 4;          // k-chunk; C/D row group
    const int n0   = nt * 64 + wv * 16;

    const float* xrow = x + ((long)bt * NN + n0 + r) * FIN;

    f32x4 acc[4] = {{0,0,0,0},{0,0,0,0},{0,0,0,0},{0,0,0,0}};

#pragma unroll
    for (int ks = 0; ks < 4; ++ks) {
        f32x4 xa = __builtin_nontemporal_load((const f32x4*)&xrow[ks * 32 + kc * 8]);
        f32x4 xb = __builtin_nontemporal_load((const f32x4*)&xrow[ks * 32 + kc * 8 + 4]);
        float xv[8] = {xa[0], xa[1], xa[2], xa[3], xb[0], xb[1], xb[2], xb[3]};
        bf16x8 Ahi, Alo;
#pragma unroll
        for (int e = 0; e < 8; ++e) {
            uint b = __float_as_uint(xv[e]);
            float hf = __uint_as_float(b & 0xFFFF0000u);
            Ahi[e] = (short)(b >> 16);
            float rr = xv[e] - hf;                       // exact (Sterbenz)
            Alo[e] = (short)(__float_as_uint(rr) >> 16); // trunc
        }
#pragma unroll
        for (int g = 0; g < 4; ++g) {
            const int wo = (g * 16 + r) * FIN + ks * 32 + kc * 8;
            bf16x8 Bhi = *(const bf16x8*)&Whi[wo];
            bf16x8 Blo = *(const bf16x8*)&Wlo[wo];
            acc[g] = __builtin_amdgcn_mfma_f32_16x16x32_bf16(Ahi, Bhi, acc[g], 0, 0, 0);
            acc[g] = __builtin_amdgcn_mfma_f32_16x16x32_bf16(Alo, Bhi, acc[g], 0, 0, 0);
            acc[g] = __builtin_amdgcn_mfma_f32_16x16x32_bf16(Ahi, Blo, acc[g], 0, 0, 0);
        }
    }

    float a1g[4], a2g[4];
#pragma unroll
    for (int g = 0; g < 4; ++g) {
        a1g[g] = a[g * 16 + r];
        a2g[g] = a[FOUT + g * 16 + r];
    }
    f32x4 s1v = {0,0,0,0}, s2v = {0,0,0,0};
#pragma unroll
    for (int g = 0; g < 4; ++g)
#pragma unroll
        for (int reg = 0; reg < 4; ++reg) {
            s1v[reg] += acc[g][reg] * a1g[g];
            s2v[reg] += acc[g][reg] * a2g[g];
        }
#pragma unroll
    for (int off = 8; off; off >>= 1)
#pragma unroll
        for (int reg = 0; reg < 4; ++reg) {
            s1v[reg] += __shfl_down(s1v[reg], off, 16);
            s2v[reg] += __shfl_down(s2v[reg], off, 16);
        }
    if (r == 0) {
        float4 o1 = make_float4(s1v[0], s1v[1], s1v[2], s1v[3]);
        float4 o2 = make_float4(s2v[0], s2v[1], s2v[2], s2v[3]);
        *(float4*)&srcv[bt * NN + n0 + kc * 4] = o1;
        *(float4*)&dstv[bt * NN + n0 + kc * 4] = o2;
    }

#pragma unroll
    for (int g = 0; g < 4; ++g) {
        uint2 pk;
        pk.x = (uint)f2bf(acc[g][0]) | ((uint)f2bf(acc[g][1]) << 16);
        pk.y = (uint)f2bf(acc[g][2]) | ((uint)f2bf(acc[g][3]) << 16);
        *(uint2*)&ht[(long)bt * (FOUT * NN) + (g * 16 + r) * NN + n0 + kc * 4] = pk;
    }
}

// 8 packed cd ushorts + dst -> A-fragment; pack via v_perm (trunc semantics).
static __device__ inline bf16x8 make_afrag(uint4 c, float4 d0, float4 d1, float si) {
    float dv[8] = {d0.x, d0.y, d0.z, d0.w, d1.x, d1.y, d1.z, d1.w};
    uint  cw[4] = {c.x, c.y, c.z, c.w};
    union { uint u[4]; bf16x8 v; } A;
#pragma unroll
    for (int q = 0; q < 4; ++q) {
        uint u = cw[q];
        float c0 = __uint_as_float((u << 16) & 0xFFFE0000u);
        float c1 = __uint_as_float(u & 0xFFFE0000u);
        float s0 = si + dv[2 * q],     lr0 = fmaxf(s0, 0.01f * s0);
        float s1 = si + dv[2 * q + 1], lr1 = fmaxf(s1, 0.01f * s1);
        float p0 = __builtin_amdgcn_exp2f(c0 * lr0);
        float p1 = __builtin_amdgcn_exp2f(c1 * lr1);
        p0 = (u & 1u)       ? p0 : 0.f;
        p1 = (u & 0x10000u) ? p1 : 0.f;
        // D = p1.hi16 : p0.hi16  (bf16 truncation, 1 instr)
        A.u[q] = __builtin_amdgcn_perm(__float_as_uint(p1), __float_as_uint(p0),
                                       0x07060302u);
    }
    return A.v;
}

// ---------- B: fused att + bf16 MFMA PV — NO LDS-B, NO staging, 1 barrier ----------
// grid 1024: bid = it*128 + bt => XCD = bt%8; ht slice (1MB/XCD) is L2-resident,
// and a B-frag is a contiguous 16B load: ht[o=g*16+r16][j0+s2*32+kc*8]. Reading B
// straight from L2 deletes hs + per-half barriers; waves are fully independent
// (only sync: dst_s fill). LDS = 2KB; VGPR <= 102 (launch_bounds 256,5) -> ~20
// waves/CU, each with ~10 loads in flight: latency hidden by TLP, not lockstep.
__global__ __launch_bounds__(256, 5)
void k_attn(const ushort* __restrict__ ht, const float* __restrict__ srcv,
            const float* __restrict__ dstv, const ushort* __restrict__ cds,
            float* __restrict__ out) {
    __shared__ float dst_s[NN];

    const int t    = threadIdx.x;
    const int bid  = blockIdx.x;
    const int bt   = bid & 127;
    const int i0   = (bid >> 7) << 6;
    const int lane = t & 63;
    const int wv   = t >> 6;             // 0..3
    const int r16  = lane & 15;
    const int kc   = lane >> 4;          // 0..3
    const int koff = kc * 8;

    const int ri = i0 + wv * 16 + r16;   // my A-row
    const float si = srcv[bt * NN + ri];
    const ushort* cdr = cds + ri * NN;
    const ushort* htb = ht + (long)bt * (FOUT * NN);
    const ushort* hb0 = htb + ( 0 + r16) * NN;   // my B-rows (o = g*16 + r16)
    const ushort* hb1 = htb + (16 + r16) * NN;
    const ushort* hb2 = htb + (32 + r16) * NN;
    const ushort* hb3 = htb + (48 + r16) * NN;

    for (int q = t; q < NN; q += 256) dst_s[q] = dstv[bt * NN + q];
    __syncthreads();   // the only barrier

    f32x4 ac0 = {0,0,0,0}, ac1 = {0,0,0,0}, ac2 = {0,0,0,0}, ac3 = {0,0,0,0},
          acd = {0,0,0,0};
    bf16x8 ones;
#pragma unroll
    for (int j = 0; j < 8; ++j) ones[j] = (short)0x3F80;   // bf16 1.0

    uint4 fA = *(const uint4*)&cdr[koff];
    uint4 fB = *(const uint4*)&cdr[32 + koff];

#pragma unroll
    for (int ch = 0; ch < 8; ++ch) {
        const int j0 = ch * 64;
        uint4 cA = fA, cB = fB;
        if (ch < 7) {                      // prefetch next chunk's cd
            fA = *(const uint4*)&cdr[j0 + 64 + koff];
            fB = *(const uint4*)&cdr[j0 + 96 + koff];
        }
        float4 d00 = *(float4*)&dst_s[j0 + koff];
        float4 d01 = *(float4*)&dst_s[j0 + koff + 4];
        float4 d10 = *(float4*)&dst_s[j0 + 32 + koff];
        float4 d11 = *(float4*)&dst_s[j0 + 32 + koff + 4];

        bf16x8 A0 = make_afrag(cA, d00, d01, si);   // s2 = 0
        bf16x8 A1 = make_afrag(cB, d10, d11, si);   // s2 = 1

#pragma unroll
        for (int s2 = 0; s2 < 2; ++s2) {
            bf16x8 A = s2 ? A1 : A0;
            const int jb = j0 + s2 * 32 + koff;      // contiguous 16B per lane
            bf16x8 b0 = *(const bf16x8*)&hb0[jb];
            bf16x8 b1 = *(const bf16x8*)&hb1[jb];
            bf16x8 b2 = *(const bf16x8*)&hb2[jb];
            bf16x8 b3 = *(const bf16x8*)&hb3[jb];
            ac0 = __builtin_amdgcn_mfma_f32_16x16x32_bf16(A, b0, ac0, 0, 0, 0);
            ac1 = __builtin_amdgcn_mfma_f32_16x16x32_bf16(A, b1, ac1, 0, 0, 0);
            ac2 = __builtin_amdgcn_mfma_f32_16x16x32_bf16(A, b2, ac2, 0, 0, 0);
            ac3 = __builtin_amdgcn_mfma_f32_16x16x32_bf16(A, b3, ac3, 0, 0, 0);
            acd = __builtin_amdgcn_mfma_f32_16x16x32_bf16(A, ones, acd, 0, 0, 0);
        }
    }

    // epilogue: C/D col=r16 (o within g*16), row=kc*4+reg (i within wave's 16)
    float* ob = out + ((long)bt * NN + i0 + wv * 16) * FOUT;
#pragma unroll
    for (int reg = 0; reg < 4; ++reg) {
        float inv = 1.0f / acd[reg];
        const int rw = (kc * 4 + reg) * FOUT + r16;
        __builtin_nontemporal_store(ac0[reg] * inv, &ob[rw +  0]);
        __builtin_nontemporal_store(ac1[reg] * inv, &ob[rw + 16]);
        __builtin_nontemporal_store(ac2[reg] * inv, &ob[rw + 32]);
        __builtin_nontemporal_store(ac3[reg] * inv, &ob[rw + 48]);
    }
}

extern "C" void kernel_launch(void* const* d_in, const int* in_sizes, int n_in,
                              void* d_out, int out_size, void* d_ws, size_t ws_size,
                              hipStream_t stream) {
    const float* x      = (const float*)d_in[0];
    const float* W      = (const float*)d_in[1];
    const float* a      = (const float*)d_in[2];
    const int*   adj    = (const int*)d_in[3];
    const float* adj_we = (const float*)d_in[4];
    float* out = (float*)d_out;

    ushort* Whi  = (ushort*)d_ws;                      // 8192 bf16
    ushort* Wlo  = Whi + FOUT * FIN;                   // 8192 bf16
    ushort* ht   = Wlo + FOUT * FIN;                   // 128*64*512 bf16
    float*  srcv = (float*)(ht + BTOT * FOUT * NN);    // 65536 fp32
    float*  dstv = srcv + BTOT * NN;                   // 65536 fp32
    ushort* cdsw = (ushort*)(dstv + BTOT * NN);        // 262144 ushorts

    hipLaunchKernelGGL(k_prep, dim3(288), dim3(256), 0, stream,
                       W, adj, adj_we, Whi, Wlo, cdsw);
    hipLaunchKernelGGL(k_feat, dim3(1024), dim3(256), 0, stream,
                       x, Whi, Wlo, a, ht, srcv, dstv);
    hipLaunchKernelGGL(k_attn, dim3(1024), dim3(256), 0, stream,
                       ht, srcv, dstv, cdsw, out);
}